// Round 9
// baseline (508.936 us; speedup 1.0000x reference)
//
#include <hip/hip_runtime.h>
#include <math.h>
#include <stdint.h>

// SoftAttention B=32, L=1024, D=256 fp32.
// R9: wave-autonomous pipeline. Each wave computes S^T = K·Q^T for its own 32
// q-rows (MFMA operand swap puts qrow on lane&31), fixes up P C-layout ->
// A-layout with 4 shfl_xor(32) per K16-block IN REGISTERS (no P LDS, no
// cross-wave dependency), then PV with V streamed from global. One barrier
// per iter (K hi/lo ping-pong staging via global_load_lds). 1 wave/SIMD by
// design (launch_bounds(256,1), ~400 regs, no spills): latency hidden by the
// wave's own MFMA-pipe overlap + 8 independent accumulator chains.

#define NB    32
#define SEQ   1024
#define DIM   256
#define BM    128
#define BN    64
#define SHIFT 60.0f

typedef unsigned int uint;
typedef unsigned short ushort;
typedef __attribute__((ext_vector_type(8)))  short short8;
typedef __attribute__((ext_vector_type(16))) float f32x16;

// ---- ws layout (per tensor: HI, LO bf16 octets [doct32][seq][8]; T bf16 V^T
//      [soct128][dim][8]) ----
#define HI_BATCH  (32 * 1024 * 8)            // ushorts
#define HI_TENSOR ((size_t)NB * HI_BATCH)    // 16 MB
#define T_BATCH   (128 * 256 * 8)            // ushorts
#define T_TENSOR  ((size_t)NB * T_BATCH)     // 16 MB
#define WS_NEED   (6 * HI_TENSOR * sizeof(ushort))   // 96 MB

__device__ __forceinline__ ushort bf16_rn(float x) {
    union { float f; uint u; } v; v.f = x;
    uint r = v.u + 0x7fffu + ((v.u >> 16) & 1u);
    return (ushort)(r >> 16);
}
__device__ __forceinline__ float bf16_to_f(ushort h) {
    union { uint u; float f; } v; v.u = ((uint)h) << 16;
    return v.f;
}
__device__ __forceinline__ void gl_lds16(const ushort* g, ushort* l) {
    __builtin_amdgcn_global_load_lds(
        (const __attribute__((address_space(1))) void*)g,
        (__attribute__((address_space(3))) void*)l, 16, 0, 0);
}

// ---------------- pre-pass: fp32 -> {bf16 hi, bf16 lo, V^T} ----------------
#define TSTR 260
__global__ __launch_bounds__(256)
void prepass(const float* __restrict__ A, const float* __restrict__ Bt,
             ushort* __restrict__ aHI, ushort* __restrict__ aLO, ushort* __restrict__ aT,
             ushort* __restrict__ bHI, ushort* __restrict__ bLO, ushort* __restrict__ bT)
{
    const int tensor = blockIdx.z;
    const float* src = tensor ? Bt : A;
    ushort* hi = tensor ? bHI : aHI;
    ushort* lo = tensor ? bLO : aLO;
    ushort* tp = tensor ? bT  : aT;
    const int batch = blockIdx.y;
    const int s0    = blockIdx.x * 32;
    const int tid   = threadIdx.x;

    __shared__ float tile[32 * TSTR];   // 33.3 KB

    // tile load (coalesced) — for the transpose phase
    const float* sb = src + ((size_t)batch * SEQ + s0) * DIM;
    #pragma unroll
    for (int i = 0; i < 8; ++i) {
        int idx = tid + i * 256;         // float4 index
        int r = idx >> 6, c = idx & 63;
        float4 v = *((const float4*)(sb + (size_t)r * DIM) + c);
        *(float4*)&tile[r * TSTR + c * 4] = v;
    }

    // phase A: hi/lo octets straight from global (L2-hot second read)
    {
        ushort* hib = hi + (size_t)batch * HI_BATCH;
        ushort* lob = lo + (size_t)batch * HI_BATCH;
        const int oct = tid >> 3;
        #pragma unroll
        for (int rr = 0; rr < 4; ++rr) {
            const int srow = (tid & 7) + rr * 8;
            const float* rp = src + ((size_t)batch * SEQ + s0 + srow) * DIM + oct * 8;
            float4 x0 = *(const float4*)rp;
            float4 x1 = *(const float4*)(rp + 4);
            float f[8] = {x0.x, x0.y, x0.z, x0.w, x1.x, x1.y, x1.z, x1.w};
            short8 hv, lv;
            #pragma unroll
            for (int j = 0; j < 8; ++j) {
                ushort hh = bf16_rn(f[j]);
                hv[j] = (short)hh;
                lv[j] = (short)bf16_rn(f[j] - bf16_to_f(hh));
            }
            *(short8*)(hib + (size_t)oct * 8192 + (size_t)(s0 + srow) * 8) = hv;
            *(short8*)(lob + (size_t)oct * 8192 + (size_t)(s0 + srow) * 8) = lv;
        }
    }
    __syncthreads();

    // phase B: V^T from LDS (lane = dim -> 2-way/free bank pattern)
    {
        ushort* tpb = tp + (size_t)batch * T_BATCH;
        const int d = tid;               // 0..255
        #pragma unroll
        for (int so = 0; so < 4; ++so) {
            short8 hv;
            #pragma unroll
            for (int j = 0; j < 8; ++j)
                hv[j] = (short)bf16_rn(tile[(so * 8 + j) * TSTR + d]);
            *(short8*)(tpb + (size_t)(blockIdx.x * 4 + so) * 2048 + (size_t)d * 8) = hv;
        }
    }
}

// ---------------- main kernel: wave-autonomous, 1 barrier/iter ----------------
__global__ __launch_bounds__(256, 1)
void attend6(const ushort* __restrict__ aHI, const ushort* __restrict__ aLO,
             const ushort* __restrict__ aT,
             const ushort* __restrict__ bHI, const ushort* __restrict__ bLO,
             const ushort* __restrict__ bT,
             const int*    __restrict__ ma,  const int*    __restrict__ mb,
             float*        __restrict__ out)
{
    __shared__ __align__(16) ushort KhiS[2 * 32 * 512];  // ping-pong, 64 KB
    __shared__ __align__(16) ushort KloS[2 * 32 * 512];  // ping-pong, 64 KB
    __shared__ float msk[SEQ];                           // 4 KB
    __shared__ float ivs[BM];                            // 512 B

    // XCD pinning: 8 row-blocks of one (batch,dir) share an XCD.
    const int bx   = blockIdx.x;        // 0..511
    const int xcd  = bx & 7;
    const int slot = bx >> 3;
    const int rb   = slot & 7;
    const int pg   = slot >> 3;
    const int pair = xcd + 8 * pg;
    const int batch = pair >> 1;
    const int dir   = pair & 1;
    const int row0  = rb * BM;

    const ushort* xHI = dir ? bHI : aHI;
    const ushort* xLO = dir ? bLO : aLO;
    const ushort* yHI = dir ? aHI : bHI;
    const ushort* yLO = dir ? aLO : bLO;
    const ushort* yT  = dir ? aT  : bT;
    const int*    mx  = dir ? mb  : ma;
    const int*    my  = dir ? ma  : mb;
    float* o = out + (size_t)dir * NB * SEQ * DIM;

    const int tid  = threadIdx.x;
    const int lane = tid & 63;
    const int wave = tid >> 6;     // 0..3: owns q-rows wave*32..wave*32+31
    const int l31  = lane & 31;
    const int h    = lane >> 5;

    const ushort* xHIb = xHI + (size_t)batch * HI_BATCH;
    const ushort* xLOb = xLO + (size_t)batch * HI_BATCH;
    const ushort* yHIb = yHI + (size_t)batch * HI_BATCH;
    const ushort* yLOb = yLO + (size_t)batch * HI_BATCH;
    const ushort* yTb  = yT  + (size_t)batch * T_BATCH;

    // stage K(0) into buffer 0: wave w stages docts w*8..w*8+7, lane = key
    #pragma unroll
    for (int i = 0; i < 8; ++i) {
        const int doct = wave * 8 + i;
        gl_lds16(yHIb + (size_t)doct * 8192 + (size_t)lane * 8, KhiS + doct * 512 + lane * 8);
        gl_lds16(yLOb + (size_t)doct * 8192 + (size_t)lane * 8, KloS + doct * 512 + lane * 8);
    }
    // key-mask preload
    for (int i = tid; i < SEQ; i += 256) msk[i] = (float)my[batch * SEQ + i];

    // Q hi/lo fragments (B-operand for S^T): n = l31 = qrow, k-oct = 2kk+h
    const int qrow = row0 + wave * 32 + l31;
    short8 qhi[16], qlo[16];
    {
        const ushort* qh = xHIb + (size_t)h * 8192 + (size_t)qrow * 8;
        const ushort* ql = xLOb + (size_t)h * 8192 + (size_t)qrow * 8;
        #pragma unroll
        for (int kk = 0; kk < 16; ++kk) {
            qhi[kk] = *(const short8*)(qh + (size_t)(2 * kk) * 8192);
            qlo[kk] = *(const short8*)(ql + (size_t)(2 * kk) * 8192);
        }
    }

    f32x16 oacc[8];
    #pragma unroll
    for (int t = 0; t < 8; ++t)
        #pragma unroll
        for (int r = 0; r < 16; ++r) oacc[t][r] = 0.f;
    float lsum = 0.f;

    __syncthreads();   // K(0) staged; msk visible

    for (int nt = 0; nt < SEQ / BN; ++nt) {
        const int cur  = nt & 1;
        const int key0 = nt * BN;
        const ushort* kh = KhiS + cur * (32 * 512);
        const ushort* kl = KloS + cur * (32 * 512);

        // prefetch K(nt+1) into the other buffer — drains at end-of-iter barrier
        if (nt + 1 < SEQ / BN) {
            ushort* nh = KhiS + (cur ^ 1) * (32 * 512);
            ushort* nl = KloS + (cur ^ 1) * (32 * 512);
            #pragma unroll
            for (int i = 0; i < 8; ++i) {
                const int doct = wave * 8 + i;
                gl_lds16(yHIb + (size_t)doct * 8192 + (size_t)(key0 + BN + lane) * 8,
                         nh + doct * 512 + lane * 8);
                gl_lds16(yLOb + (size_t)doct * 8192 + (size_t)(key0 + BN + lane) * 8,
                         nl + doct * 512 + lane * 8);
            }
        }

        // ---- S^T = K·Q^T (two 32-key blocks): hi chain + merged correction ----
        f32x16 c0h, c0c, c1h, c1c;
        #pragma unroll
        for (int r = 0; r < 16; ++r) { c0h[r] = 0.f; c0c[r] = 0.f; c1h[r] = 0.f; c1c[r] = 0.f; }
        #pragma unroll
        for (int kk = 0; kk < 16; ++kk) {
            const int off = (2 * kk + h) * 512;
            short8 k0h = *(const short8*)&kh[off + l31 * 8];
            short8 k1h = *(const short8*)&kh[off + (32 + l31) * 8];
            short8 k0l = *(const short8*)&kl[off + l31 * 8];
            short8 k1l = *(const short8*)&kl[off + (32 + l31) * 8];
            c0h = __builtin_amdgcn_mfma_f32_32x32x16_bf16(k0h, qhi[kk], c0h, 0, 0, 0);
            c1h = __builtin_amdgcn_mfma_f32_32x32x16_bf16(k1h, qhi[kk], c1h, 0, 0, 0);
            c0c = __builtin_amdgcn_mfma_f32_32x32x16_bf16(k0l, qhi[kk], c0c, 0, 0, 0);
            c0c = __builtin_amdgcn_mfma_f32_32x32x16_bf16(k0h, qlo[kk], c0c, 0, 0, 0);
            c1c = __builtin_amdgcn_mfma_f32_32x32x16_bf16(k1l, qhi[kk], c1c, 0, 0, 0);
            c1c = __builtin_amdgcn_mfma_f32_32x32x16_bf16(k1h, qlo[kk], c1c, 0, 0, 0);
        }

        // ---- exp + mask; C-layout: lane holds (qrow=l31, key=(r&3)+8(r>>2)+4h) ----
        float pe[2][16];
        #pragma unroll
        for (int r = 0; r < 16; ++r) {
            const int kloc = (r & 3) + 8 * (r >> 2) + 4 * h;
            float m0 = msk[key0 + kloc];
            float m1 = msk[key0 + 32 + kloc];
            float p0 = __expf(c0h[r] + c0c[r] - SHIFT) * m0;
            float p1 = __expf(c1h[r] + c1c[r] - SHIFT) * m1;
            lsum += p0 + p1;
            pe[0][r] = p0;
            pe[1][r] = p1;
        }

        // ---- C-layout -> PV A-frags via lane-pair exchange (no LDS) ----
        // A-frag kb needs keys 16kb+8h+j at slot j; source reg = 8(kb&1)+4h+j
        // from half h_src = (j<4 ? 0 : 1).
        short8 pf[4];
        #pragma unroll
        for (int kb = 0; kb < 4; ++kb) {
            #pragma unroll
            for (int j = 0; j < 4; ++j) {
                float x = pe[kb >> 1][8 * (kb & 1) + j];        // own, h=0 role
                float y = pe[kb >> 1][8 * (kb & 1) + 4 + j];    // own, h=1 role
                float send = h ? x : y;
                float recv = __shfl_xor(send, 32, 64);
                float aj  = h ? recv : x;
                float aj4 = h ? y : recv;
                pf[kb][j]     = (short)bf16_rn(aj);
                pf[kb][j + 4] = (short)bf16_rn(aj4);
            }
        }

        // ---- PV: oacc[t] += P·V ; V B-frags streamed from global (L1/L2-hot) ----
        #pragma unroll
        for (int kb = 0; kb < 4; ++kb) {
            const ushort* vb = yTb + (size_t)(nt * 8 + 2 * kb + h) * 2048;
            #pragma unroll
            for (int t = 0; t < 8; ++t) {
                short8 vf = *(const short8*)(vb + (size_t)(t * 32 + l31) * 8);
                oacc[t] = __builtin_amdgcn_mfma_f32_32x32x16_bf16(pf[kb], vf, oacc[t], 0, 0, 0);
            }
        }

        __syncthreads();   // all waves done with buf cur; prefetch drained
    }

    // ---- epilogue: l reduce (lane-pair), normalize, coalesced store ----
    float ltot = lsum + __shfl_xor(lsum, 32, 64);
    if (lane < 32) {
        int row = wave * 32 + lane;
        int valid = mx[batch * SEQ + row0 + row];
        ivs[row] = (valid != 0 && ltot > 0.f) ? 1.f / ltot : 0.f;
    }
    // ivs written and read by the same wave only — no barrier needed
    float* ob = o + ((size_t)batch * SEQ + row0 + wave * 32) * DIM;
    #pragma unroll
    for (int r = 0; r < 16; ++r) {
        const int rl = (r & 3) + 8 * (r >> 2) + 4 * h;   // 0..31 within wave
        float inv = ivs[wave * 32 + rl];
        #pragma unroll
        for (int t = 0; t < 8; ++t)
            ob[(size_t)rl * DIM + t * 32 + l31] = oacc[t][r] * inv;
    }
}

// ---------------- fallback (R2 kernel, known-good) if ws too small ----------------
#define F_KS_STR 520
#define F_P_STR  136
#define F_BM 64
#define F_BN 64
__global__ __launch_bounds__(256, 1)
void attend_mfma(const float* __restrict__ X, const float* __restrict__ Y,
                 const int* __restrict__ mx, const int* __restrict__ my,
                 float* __restrict__ out)
{
    __shared__ ushort Ks[F_BN * F_KS_STR];
    __shared__ ushort Ps[F_BM * F_P_STR];
    __shared__ float  mk[F_BN];
    __shared__ float  lpart[2][F_BM];
    __shared__ float  invs[F_BM];

    const int tid = threadIdx.x, lane = tid & 63, wave = tid >> 6;
    const int l31 = lane & 31, lh = lane >> 5;
    const int rw = wave >> 1, cw = wave & 1;
    const int batch = blockIdx.y, row0 = blockIdx.x * F_BM;
    const float* Xb = X + (size_t)batch * SEQ * DIM;
    const float* Yb = Y + (size_t)batch * SEQ * DIM;

    float4 kreg[16]; int mreg = 0;
    #pragma unroll
    for (int i = 0; i < 16; ++i) {
        int idx = tid + (i << 8); int r = idx >> 6, c4 = idx & 63;
        kreg[i] = *((const float4*)(Yb + (size_t)r * DIM) + c4);
    }
    if (tid < F_BN) mreg = my[batch * SEQ + tid];

    short8 qhi[16], qlo[16];
    {
        const float* qrow = Xb + (size_t)(row0 + rw * 32 + l31) * DIM + lh * 8;
        #pragma unroll
        for (int kk = 0; kk < 16; ++kk) {
            const float* p = qrow + kk * 16;
            float4 x0 = *(const float4*)p; float4 x1 = *(const float4*)(p + 4);
            float xs[8] = {x0.x, x0.y, x0.z, x0.w, x1.x, x1.y, x1.z, x1.w};
            #pragma unroll
            for (int j = 0; j < 8; ++j) {
                ushort hh = bf16_rn(xs[j]);
                qhi[kk][j] = (short)hh;
                qlo[kk][j] = (short)bf16_rn(xs[j] - bf16_to_f(hh));
            }
        }
    }
    f32x16 oacc[4];
    #pragma unroll
    for (int t = 0; t < 4; ++t)
        #pragma unroll
        for (int r = 0; r < 16; ++r) oacc[t][r] = 0.f;
    float lsum[16];
    #pragma unroll
    for (int r = 0; r < 16; ++r) lsum[r] = 0.f;

    for (int nt = 0; nt < SEQ / F_BN; ++nt) {
        if (nt) __syncthreads();
        #pragma unroll
        for (int i = 0; i < 16; ++i) {
            int idx = tid + (i << 8); int r = idx >> 6, c4 = idx & 63;
            float f[4] = {kreg[i].x, kreg[i].y, kreg[i].z, kreg[i].w};
            ushort hh[4], ll[4];
            #pragma unroll
            for (int q = 0; q < 4; ++q) { hh[q] = bf16_rn(f[q]); ll[q] = bf16_rn(f[q] - bf16_to_f(hh[q])); }
            ushort4 hv; hv.x=hh[0];hv.y=hh[1];hv.z=hh[2];hv.w=hh[3];
            ushort4 lv; lv.x=ll[0];lv.y=ll[1];lv.z=ll[2];lv.w=ll[3];
            *(ushort4*)&Ks[r * F_KS_STR + c4 * 4] = hv;
            *(ushort4*)&Ks[r * F_KS_STR + 256 + c4 * 4] = lv;
        }
        if (tid < F_BN) mk[tid] = (float)mreg;
        __syncthreads();
        if (nt + 1 < SEQ / F_BN) {
            const float* Ybn = Yb + (size_t)(nt + 1) * F_BN * DIM;
            #pragma unroll
            for (int i = 0; i < 16; ++i) {
                int idx = tid + (i << 8); int r = idx >> 6, c4 = idx & 63;
                kreg[i] = *((const float4*)(Ybn + (size_t)r * DIM) + c4);
            }
            if (tid < F_BN) mreg = my[batch * SEQ + (nt + 1) * F_BN + tid];
        }
        f32x16 a1, a2, a3;
        #pragma unroll
        for (int r = 0; r < 16; ++r) { a1[r]=0.f; a2[r]=0.f; a3[r]=0.f; }
        const int krow = (cw * 32 + l31) * F_KS_STR;
        #pragma unroll
        for (int kk = 0; kk < 16; ++kk) {
            int col = kk * 16 + lh * 8;
            short8 bhi = *(const short8*)&Ks[krow + col];
            short8 blo = *(const short8*)&Ks[krow + 256 + col];
            a1 = __builtin_amdgcn_mfma_f32_32x32x16_bf16(qhi[kk], bhi, a1, 0, 0, 0);
            a2 = __builtin_amdgcn_mfma_f32_32x32x16_bf16(qlo[kk], bhi, a2, 0, 0, 0);
            a3 = __builtin_amdgcn_mfma_f32_32x32x16_bf16(qhi[kk], blo, a3, 0, 0, 0);
        }
        const float mkv = mk[cw * 32 + l31];
        #pragma unroll
        for (int r = 0; r < 16; ++r) {
            float s = a1[r] + a2[r] + a3[r];
            float p = __expf(s - SHIFT) * mkv;
            lsum[r] += p;
            ushort ph = bf16_rn(p);
            ushort pl = bf16_rn(p - bf16_to_f(ph));
            int prow = rw * 32 + (r & 3) + ((r >> 2) << 3) + (lh << 2);
            int pcol = cw * 32 + l31;
            Ps[prow * F_P_STR + pcol] = ph;
            Ps[prow * F_P_STR + 64 + pcol] = pl;
        }
        __syncthreads();
        const int prow = (rw * 32 + l31) * F_P_STR;
        #pragma unroll
        for (int kb = 0; kb < 4; ++kb) {
            int pcol = kb * 16 + lh * 8;
            short8 pa_hi = *(const short8*)&Ps[prow + pcol];
            short8 pa_lo = *(const short8*)&Ps[prow + 64 + pcol];
            #pragma unroll
            for (int t = 0; t < 4; ++t) {
                int d0 = cw * 128 + t * 32 + l31;
                short8 vf;
                #pragma unroll
                for (int j = 0; j < 8; ++j) vf[j] = (short)Ks[(pcol + j) * F_KS_STR + d0];
                oacc[t] = __builtin_amdgcn_mfma_f32_32x32x16_bf16(pa_hi, vf, oacc[t], 0, 0, 0);
                oacc[t] = __builtin_amdgcn_mfma_f32_32x32x16_bf16(pa_lo, vf, oacc[t], 0, 0, 0);
            }
        }
    }
    #pragma unroll
    for (int r = 0; r < 16; ++r) {
        float v = lsum[r];
        v += __shfl_xor(v, 1, 64); v += __shfl_xor(v, 2, 64); v += __shfl_xor(v, 4, 64);
        v += __shfl_xor(v, 8, 64); v += __shfl_xor(v, 16, 64);
        if (l31 == 0) {
            int row = rw * 32 + (r & 3) + ((r >> 2) << 3) + (lh << 2);
            lpart[cw][row] = v;
        }
    }
    __syncthreads();
    if (tid < F_BM) {
        float l = lpart[0][tid] + lpart[1][tid];
        int valid = mx[batch * SEQ + row0 + tid];
        invs[tid] = (valid != 0 && l > 0.f) ? 1.f / l : 0.f;
    }
    __syncthreads();
    float* ob = out + ((size_t)batch * SEQ + row0) * DIM;
    #pragma unroll
    for (int r = 0; r < 16; ++r) {
        int rloc = rw * 32 + (r & 3) + ((r >> 2) << 3) + (lh << 2);
        float inv = invs[rloc];
        #pragma unroll
        for (int t = 0; t < 4; ++t) {
            int d = cw * 128 + t * 32 + l31;
            ob[(size_t)rloc * DIM + d] = oacc[t][r] * inv;
        }
    }
}

extern "C" void kernel_launch(void* const* d_in, const int* in_sizes, int n_in,
                              void* d_out, int out_size, void* d_ws, size_t ws_size,
                              hipStream_t stream) {
    const float* a  = (const float*)d_in[0];
    const float* b  = (const float*)d_in[1];
    const int*   ma = (const int*)d_in[2];
    const int*   mb = (const int*)d_in[3];
    float* out = (float*)d_out;

    if (ws_size >= WS_NEED) {
        char* w = (char*)d_ws;
        ushort* aHI = (ushort*)(w + 0 * 16 * 1024 * 1024);
        ushort* aLO = (ushort*)(w + 1 * 16 * 1024 * 1024);
        ushort* aT  = (ushort*)(w + 2 * 16 * 1024 * 1024);
        ushort* bHI = (ushort*)(w + 3 * 16 * 1024 * 1024);
        ushort* bLO = (ushort*)(w + 4 * 16 * 1024 * 1024);
        ushort* bT  = (ushort*)(w + 5 * 16 * 1024 * 1024);

        prepass<<<dim3(SEQ / 32, NB, 2), 256, 0, stream>>>(a, b, aHI, aLO, aT, bHI, bLO, bT);
        attend6<<<dim3(512, 1, 1), 256, 0, stream>>>(aHI, aLO, aT, bHI, bLO, bT, ma, mb, out);
    } else {
        float* out_a = out;
        float* out_b = out + (size_t)NB * SEQ * DIM;
        dim3 grid(SEQ / F_BM, NB), block(256);
        attend_mfma<<<grid, block, 0, stream>>>(a, b, ma, mb, out_a);
        attend_mfma<<<grid, block, 0, stream>>>(b, a, mb, ma, out_b);
    }
}